// Round 2
// baseline (5346.287 us; speedup 1.0000x reference)
//
#include <hip/hip_runtime.h>

// RecurrentTransformerEncoder on MI355X — round 10: persistent phase-2 kernel
// launched as a PLAIN kernel (round-9's hipLaunchCooperativeKernel was dropped
// under graph capture -> output never written). Co-residency of the 512-block
// grid is validated via hipOccupancyMaxActiveBlocksPerMultiprocessor (host-side
// query, capture-safe); barrier counter is zeroed by lens_k (kernel node, runs
// every replay); gbar has a bounded spin as a deadlock escape hatch.
// B=64, T=16, SEG=50, E=D=512, H=8, DH=64, F=2048.

#define NB   64
#define NT   16
#define SEGL 50
#define DMODEL 512
#define DFF  2048
#define NHEAD 8
#define DHEAD 64

typedef unsigned short ushort_t;
typedef __attribute__((ext_vector_type(8))) short bfrag;   // 8 bf16 (4 VGPRs)
typedef __attribute__((ext_vector_type(4))) float ffrag;   // 4 fp32 acc

__device__ __forceinline__ ushort_t f2b(float x) {
    union { float f; unsigned u; } c; c.f = x;
    unsigned r = c.u + 0x7fffu + ((c.u >> 16) & 1u);
    return (ushort_t)(r >> 16);
}

#define GLOAD_LDS16(g, l) __builtin_amdgcn_global_load_lds( \
    (const __attribute__((address_space(1))) void*)(g),      \
    (__attribute__((address_space(3))) void*)(l), 16, 0, 0)

// ---------------------------------------------------------------------------
// MFMA GEMM (LDS-staged, BK=64 dbuf): C = relu?(A @ Bt^T), bf16.
// A rows remapped: row m at A + (m/agrp)*astride + (m%agrp)*K.
// Used for the big phase-1 GEMMs (128x128 tiles).
// ---------------------------------------------------------------------------
template<int BM, int BN, int WROWS, int WCOLS>
__global__ __launch_bounds__(256) void mfma_gemm(
    const ushort_t* __restrict__ A, int agrp, long long astride,
    const ushort_t* __restrict__ Bt, ushort_t* __restrict__ C,
    int M, int N, int K, int relu)
{
    constexpr int WM = BM / WROWS, WN = BN / WCOLS;
    constexpr int SM = WM / 16, SN = WN / 16;
    constexpr int NSUBA = BM / 16, NSUBB = BN / 16;
    constexpr int NSUB = NSUBA + NSUBB;
    constexpr int NINST = NSUB * 2;
    constexpr int IPW = NINST / 4;
    constexpr int BUFS = NSUB * 1024;
    constexpr int EST = WN + 8;
    constexpr int LDS_KLOOP = 2 * BUFS;
    constexpr int LDS_EPI   = 4 * WM * EST;
    constexpr int LDS_SZ = LDS_KLOOP > LDS_EPI ? LDS_KLOOP : LDS_EPI;
    __shared__ ushort_t lds[LDS_SZ];

    const int tid = threadIdx.x;
    const int wave = tid >> 6, lane = tid & 63;
    const int wrow = wave / WCOLS, wcol = wave % WCOLS;
    const int bm = blockIdx.y * BM, bn = blockIdx.x * BN;
    const int lm = lane & 15, lq = lane >> 4;

    ffrag acc[SM][SN];
#pragma unroll
    for (int i = 0; i < SM; ++i)
#pragma unroll
        for (int j = 0; j < SN; ++j) acc[i][j] = (ffrag){0.f, 0.f, 0.f, 0.f};

    const ushort_t* gptr[IPW];
    int loff[IPW];
#pragma unroll
    for (int e = 0; e < IPW; ++e) {
        int g = wave * IPW + e;
        int s = g >> 1, h = g & 1;
        if (s < NSUBA) {
            int m = bm + s * 16 + lm;
            gptr[e] = A + (long long)(m / agrp) * astride
                        + (long long)(m % agrp) * K + h * 32 + lq * 8;
        } else {
            int n = bn + (s - NSUBA) * 16 + lm;
            gptr[e] = Bt + (long long)n * K + h * 32 + lq * 8;
        }
        loff[e] = s * 1024 + h * 512;
    }

#pragma unroll
    for (int e = 0; e < IPW; ++e)
        GLOAD_LDS16(gptr[e], &lds[loff[e]]);

    const int nk = K >> 6;
    for (int kk = 0; kk < nk; ++kk) {
        __syncthreads();
        if (kk + 1 < nk) {
            const int koff = (kk + 1) << 6;
            const int nb = (kk + 1) & 1;
#pragma unroll
            for (int e = 0; e < IPW; ++e)
                GLOAD_LDS16(gptr[e] + koff, &lds[nb * BUFS + loff[e]]);
        }
        const ushort_t* lb = &lds[(kk & 1) * BUFS];
#pragma unroll
        for (int h = 0; h < 2; ++h) {
            bfrag af[SM], bfg[SN];
#pragma unroll
            for (int i = 0; i < SM; ++i)
                af[i] = *(const bfrag*)&lb[(wrow * SM + i) * 1024 + h * 512 + lane * 8];
#pragma unroll
            for (int j = 0; j < SN; ++j)
                bfg[j] = *(const bfrag*)&lb[(NSUBA + wcol * SN + j) * 1024 + h * 512 + lane * 8];
#pragma unroll
            for (int i = 0; i < SM; ++i)
#pragma unroll
                for (int j = 0; j < SN; ++j)
                    acc[i][j] = __builtin_amdgcn_mfma_f32_16x16x32_bf16(
                        af[i], bfg[j], acc[i][j], 0, 0, 0);
        }
    }

    __syncthreads();
    ushort_t* ep = &lds[wave * WM * EST];
#pragma unroll
    for (int i = 0; i < SM; ++i)
#pragma unroll
        for (int j = 0; j < SN; ++j)
#pragma unroll
            for (int r = 0; r < 4; ++r) {
                int row = i * 16 + lq * 4 + r;
                int col = j * 16 + lm;
                float v = acc[i][j][r];
                if (relu) v = fmaxf(v, 0.f);
                ep[row * EST + col] = f2b(v);
            }
    constexpr int CPR = WN / 8;
    constexpr int RPI = 64 / CPR;
    const int lrow = lane / CPR, lcol = (lane % CPR) * 8;
#pragma unroll
    for (int it = 0; it < WM / RPI; ++it) {
        int row = it * RPI + lrow;
        uint4 v = *(const uint4*)&ep[row * EST + lcol];
        long long grow = bm + wrow * WM + row;
        int gcol = bn + wcol * WN + lcol;
        *(uint4*)&C[grow * N + gcol] = v;
    }
}

// ---------------------------------------------------------------------------
__global__ __launch_bounds__(256) void wtrans_k(
    const float* __restrict__ W, ushort_t* __restrict__ Wt, int K, int N)
{
    __shared__ float t[32][33];
    const int bk = blockIdx.y * 32, bn = blockIdx.x * 32;
    const int tx = threadIdx.x & 31, ty = threadIdx.x >> 5;
    for (int i = ty; i < 32; i += 8)
        t[i][tx] = W[(long long)(bk + i) * N + bn + tx];
    __syncthreads();
    for (int i = ty; i < 32; i += 8)
        Wt[(long long)(bn + i) * K + bk + tx] = f2b(t[tx][i]);
}

__global__ __launch_bounds__(256) void cvt_k(
    const float* __restrict__ in, ushort_t* __restrict__ out, long long n)
{
    long long i = ((long long)blockIdx.x * 256 + threadIdx.x) * 8;
    if (i >= n) return;
    float4 a = *(const float4*)(in + i);
    float4 b = *(const float4*)(in + i + 4);
    ushort_t o[8] = {f2b(a.x), f2b(a.y), f2b(a.z), f2b(a.w),
                     f2b(b.x), f2b(b.y), f2b(b.z), f2b(b.w)};
    *(uint4*)(out + i) = *(const uint4*)o;
}

// ---------------------------------------------------------------------------
// Phase-1 MFMA attention, one (sequence n, head h) per block. S=50->64, D=64.
// ---------------------------------------------------------------------------
__global__ __launch_bounds__(256) void attn_mfma_k(
    const ushort_t* __restrict__ Q, long long qns, long long qrs,
    const ushort_t* __restrict__ K, const ushort_t* __restrict__ V,
    long long kns, long long kvrs,
    ushort_t* __restrict__ O,
    const int* __restrict__ lens, int G, int t0)
{
    __shared__ ushort_t qs[64][72];   // Q, then P
    __shared__ ushort_t ks[64][72];
    __shared__ ushort_t vt[64][72];   // V^T
    const int n = blockIdx.x >> 3, h = blockIdx.x & 7;
    const int tid = threadIdx.x;
    const int wave = tid >> 6, lane = tid & 63;
    const int lm = lane & 15, lq = lane >> 4;
    int len = SEGL;
    if (lens) {
        int b = n / G, t = t0 + (n % G);
        len = lens[b * NT + t];
        if (len > SEGL) len = SEGL;
    }
    {
        uint4 z = {0, 0, 0, 0};
        uint4* vz = (uint4*)&vt[0][0];
        for (int i = tid; i < 64 * 72 / 8; i += 256) vz[i] = z;
    }
    __syncthreads();
    for (int idx = tid; idx < SEGL * 8; idx += 256) {
        int s = idx >> 3, d8 = (idx & 7) << 3;
        const ushort_t* qp = Q + (long long)n * qns + (long long)s * qrs + h * DHEAD + d8;
        const ushort_t* kp = K + (long long)n * kns + (long long)s * kvrs + h * DHEAD + d8;
        const ushort_t* vp = V + (long long)n * kns + (long long)s * kvrs + h * DHEAD + d8;
        *(uint4*)&qs[s][d8] = *(const uint4*)qp;
        *(uint4*)&ks[s][d8] = *(const uint4*)kp;
        uint4 v4 = *(const uint4*)vp;
        const ushort_t* vv = (const ushort_t*)&v4;
#pragma unroll
        for (int u = 0; u < 8; ++u) vt[d8 + u][s] = vv[u];
    }
    __syncthreads();

    ffrag sc[4];
#pragma unroll
    for (int nt = 0; nt < 4; ++nt) sc[nt] = (ffrag){0.f, 0.f, 0.f, 0.f};
#pragma unroll
    for (int kt = 0; kt < 2; ++kt) {
        bfrag a = *(const bfrag*)&qs[wave * 16 + lm][kt * 32 + lq * 8];
#pragma unroll
        for (int nt = 0; nt < 4; ++nt) {
            bfrag b = *(const bfrag*)&ks[nt * 16 + lm][kt * 32 + lq * 8];
            sc[nt] = __builtin_amdgcn_mfma_f32_16x16x32_bf16(a, b, sc[nt], 0, 0, 0);
        }
    }
    __syncthreads();

#pragma unroll
    for (int r = 0; r < 4; ++r) {
        float x[4];
        float mx = -1e30f;
#pragma unroll
        for (int nt = 0; nt < 4; ++nt) {
            int col = nt * 16 + lm;
            x[nt] = (col < len) ? sc[nt][r] * 0.125f : -1e9f;
            mx = fmaxf(mx, x[nt]);
        }
        for (int off = 8; off; off >>= 1) mx = fmaxf(mx, __shfl_xor(mx, off));
        float e[4], se = 0.f;
#pragma unroll
        for (int nt = 0; nt < 4; ++nt) { e[nt] = __expf(x[nt] - mx); se += e[nt]; }
        for (int off = 8; off; off >>= 1) se += __shfl_xor(se, off);
        float inv = 1.f / se;
        int row = wave * 16 + lq * 4 + r;
#pragma unroll
        for (int nt = 0; nt < 4; ++nt)
            qs[row][nt * 16 + lm] = f2b(e[nt] * inv);
    }
    __syncthreads();

    ffrag oc[4];
#pragma unroll
    for (int dt = 0; dt < 4; ++dt) oc[dt] = (ffrag){0.f, 0.f, 0.f, 0.f};
#pragma unroll
    for (int kt = 0; kt < 2; ++kt) {
        bfrag a = *(const bfrag*)&qs[wave * 16 + lm][kt * 32 + lq * 8];
#pragma unroll
        for (int dt = 0; dt < 4; ++dt) {
            bfrag b = *(const bfrag*)&vt[dt * 16 + lm][kt * 32 + lq * 8];
            oc[dt] = __builtin_amdgcn_mfma_f32_16x16x32_bf16(a, b, oc[dt], 0, 0, 0);
        }
    }
#pragma unroll
    for (int r = 0; r < 4; ++r) {
        int i = wave * 16 + lq * 4 + r;
        if (i < SEGL) {
            ushort_t* op = O + (long long)(n * SEGL + i) * DMODEL + h * DHEAD + lm;
#pragma unroll
            for (int dt = 0; dt < 4; ++dt)
                op[dt * 16] = f2b(oc[dt][r]);
        }
    }
}

// ---------------------------------------------------------------------------
// out = LN(a + b)*gamma + beta, rows of 512, bf16 in, bf16/fp32 out. (phase 1)
// ---------------------------------------------------------------------------
template<bool OUTF32>
__global__ __launch_bounds__(256) void add_ln_k(
    const ushort_t* __restrict__ A, int agrp, long long astride,
    const ushort_t* __restrict__ Bv,
    const float* __restrict__ gamma, const float* __restrict__ beta,
    void* __restrict__ O, int ogrp, long long ostride, int M)
{
    const int wave = threadIdx.x >> 6, lane = threadIdx.x & 63;
    const int r = blockIdx.x * 4 + wave;
    if (r >= M) return;
    const ushort_t* a = A + (long long)(r / agrp) * astride + (long long)(r % agrp) * DMODEL;
    const ushort_t* b = Bv + (long long)r * DMODEL;
    float x[8];
    {
        uint4 a4 = *(const uint4*)(a + lane * 8);
        uint4 b4 = *(const uint4*)(b + lane * 8);
        const unsigned* aa = (const unsigned*)&a4;
        const unsigned* bb = (const unsigned*)&b4;
#pragma unroll
        for (int c = 0; c < 4; ++c) {
            union { unsigned u; float f; } alo, ahi, blo, bhi;
            alo.u = aa[c] << 16; ahi.u = aa[c] & 0xffff0000u;
            blo.u = bb[c] << 16; bhi.u = bb[c] & 0xffff0000u;
            x[2 * c]     = alo.f + blo.f;
            x[2 * c + 1] = ahi.f + bhi.f;
        }
    }
    float s = 0.f, s2 = 0.f;
#pragma unroll
    for (int i = 0; i < 8; ++i) { s += x[i]; s2 = fmaf(x[i], x[i], s2); }
    for (int off = 32; off; off >>= 1) {
        s += __shfl_xor(s, off);
        s2 += __shfl_xor(s2, off);
    }
    const float mean = s * (1.f / DMODEL);
    const float var = s2 * (1.f / DMODEL) - mean * mean;
    const float inv = rsqrtf(var + 1e-5f);
    float4 g0 = *(const float4*)(gamma + lane * 8);
    float4 g1 = *(const float4*)(gamma + lane * 8 + 4);
    float4 be0 = *(const float4*)(beta + lane * 8);
    float4 be1 = *(const float4*)(beta + lane * 8 + 4);
    float y[8];
    y[0] = (x[0] - mean) * inv * g0.x + be0.x;
    y[1] = (x[1] - mean) * inv * g0.y + be0.y;
    y[2] = (x[2] - mean) * inv * g0.z + be0.z;
    y[3] = (x[3] - mean) * inv * g0.w + be0.w;
    y[4] = (x[4] - mean) * inv * g1.x + be1.x;
    y[5] = (x[5] - mean) * inv * g1.y + be1.y;
    y[6] = (x[6] - mean) * inv * g1.z + be1.z;
    y[7] = (x[7] - mean) * inv * g1.w + be1.w;
    if (OUTF32) {
        float* o = (float*)O + (long long)(r / ogrp) * ostride + (long long)(r % ogrp) * DMODEL;
        *(float4*)(o + lane * 8) = *(float4*)&y[0];
        *(float4*)(o + lane * 8 + 4) = *(float4*)&y[4];
    } else {
        ushort_t* o = (ushort_t*)O + (long long)(r / ogrp) * ostride + (long long)(r % ogrp) * DMODEL;
        ushort_t ob[8];
#pragma unroll
        for (int i = 0; i < 8; ++i) ob[i] = f2b(y[i]);
        *(uint4*)(o + lane * 8) = *(const uint4*)ob;
    }
}

// lens + barrier reset (kernel node -> runs on every graph replay, in stream
// order before phase2_k).
__global__ void lens_k(const int* __restrict__ ends, int* __restrict__ lens,
                       unsigned* __restrict__ bar)
{
    int i = blockIdx.x * 256 + threadIdx.x;
    if (blockIdx.x == 0 && threadIdx.x == 0) *bar = 0;
    if (i >= NB * NT) return;
    int t = i & (NT - 1);
    int prev = t ? ends[i - 1] : 0;
    int l = ends[i] - prev;
    if (l > SEGL) l = SEGL;
    lens[i] = l;
}

// ===========================================================================
// Persistent phase-2: device-side ports of the per-step kernels.
// ===========================================================================

// Device-scope grid barrier: monotonic counter (zeroed by lens_k each launch).
// target = (#barriers so far) * gridDim.x. Requires all blocks co-resident;
// grid size is validated host-side via the occupancy API. Bounded spin (2^20
// sleeps ~ 0.25s) turns a co-residency failure into a visible wrong-answer
// instead of a hang.
__device__ __forceinline__ void gbar(unsigned* bar, unsigned target)
{
    __syncthreads();                       // all waves drain their mem ops
    if (threadIdx.x == 0) {
        __threadfence();                   // release: flush XCD L2
        __hip_atomic_fetch_add(bar, 1u, __ATOMIC_RELAXED, __HIP_MEMORY_SCOPE_AGENT);
        int spins = 0;
        while (__hip_atomic_load(bar, __ATOMIC_RELAXED, __HIP_MEMORY_SCOPE_AGENT) < target) {
            __builtin_amdgcn_s_sleep(8);
            if (++spins > (1 << 20)) break;    // escape hatch
        }
        __threadfence();                   // acquire: invalidate L1/L2
    }
    __syncthreads();
}

// 64x64-tile GEMM unit (== mfma_gemm<64,64,2,2> body), u = by*(N/64)+bx.
// Uses smem[0 .. 16384) ushorts. __syncthreads at entry guards LDS reuse.
__device__ void dev_gemm64(ushort_t* lds, int u,
    const ushort_t* __restrict__ A, int agrp, long long astride,
    const ushort_t* __restrict__ Bt, ushort_t* __restrict__ C,
    int M, int N, int K, int relu)
{
    const int tid = threadIdx.x;
    const int wave = tid >> 6, lane = tid & 63;
    const int wrow = wave >> 1, wcol = wave & 1;
    const int nbx = N >> 6;
    const int bm = (u / nbx) << 6, bn = (u % nbx) << 6;
    const int lm = lane & 15, lq = lane >> 4;

    __syncthreads();   // previous unit's LDS reads done before we overwrite

    ffrag acc[2][2];
#pragma unroll
    for (int i = 0; i < 2; ++i)
#pragma unroll
        for (int j = 0; j < 2; ++j) acc[i][j] = (ffrag){0.f, 0.f, 0.f, 0.f};

    const ushort_t* gptr[4];
    int loff[4];
#pragma unroll
    for (int e = 0; e < 4; ++e) {
        int g = wave * 4 + e;
        int s = g >> 1, h = g & 1;
        if (s < 4) {
            int m = bm + s * 16 + lm;
            gptr[e] = A + (long long)(m / agrp) * astride
                        + (long long)(m % agrp) * K + h * 32 + lq * 8;
        } else {
            int n = bn + (s - 4) * 16 + lm;
            gptr[e] = Bt + (long long)n * K + h * 32 + lq * 8;
        }
        loff[e] = s * 1024 + h * 512;
    }

#pragma unroll
    for (int e = 0; e < 4; ++e)
        GLOAD_LDS16(gptr[e], &lds[loff[e]]);

    const int nk = K >> 6;
    for (int kk = 0; kk < nk; ++kk) {
        __syncthreads();
        if (kk + 1 < nk) {
            const int koff = (kk + 1) << 6;
            const int nb = (kk + 1) & 1;
#pragma unroll
            for (int e = 0; e < 4; ++e)
                GLOAD_LDS16(gptr[e] + koff, &lds[nb * 8192 + loff[e]]);
        }
        const ushort_t* lb = &lds[(kk & 1) * 8192];
#pragma unroll
        for (int h = 0; h < 2; ++h) {
            bfrag af[2], bfg[2];
#pragma unroll
            for (int i = 0; i < 2; ++i)
                af[i] = *(const bfrag*)&lb[(wrow * 2 + i) * 1024 + h * 512 + lane * 8];
#pragma unroll
            for (int j = 0; j < 2; ++j)
                bfg[j] = *(const bfrag*)&lb[(4 + wcol * 2 + j) * 1024 + h * 512 + lane * 8];
#pragma unroll
            for (int i = 0; i < 2; ++i)
#pragma unroll
                for (int j = 0; j < 2; ++j)
                    acc[i][j] = __builtin_amdgcn_mfma_f32_16x16x32_bf16(
                        af[i], bfg[j], acc[i][j], 0, 0, 0);
        }
    }

    __syncthreads();
    ushort_t* ep = &lds[wave * 32 * 40];
#pragma unroll
    for (int i = 0; i < 2; ++i)
#pragma unroll
        for (int j = 0; j < 2; ++j)
#pragma unroll
            for (int r = 0; r < 4; ++r) {
                int row = i * 16 + lq * 4 + r;
                int col = j * 16 + lm;
                float v = acc[i][j][r];
                if (relu) v = fmaxf(v, 0.f);
                ep[row * 40 + col] = f2b(v);
            }
    // same-wave LDS write->read: ordered, no barrier needed
    const int lrow = lane >> 2, lcol = (lane & 3) * 8;
#pragma unroll
    for (int it = 0; it < 2; ++it) {
        int row = it * 16 + lrow;
        uint4 v = *(const uint4*)&ep[row * 40 + lcol];
        long long grow = bm + wrow * 32 + row;
        int gcol = bn + wcol * 32 + lcol;
        *(uint4*)&C[grow * N + gcol] = v;
    }
}

// Fused KV-projection + cross-attention unit (== cross_attn_k body).
// Uses smem[0 .. 21504) ushorts: xp = 64*264, qs = 64*72.
__device__ void dev_cross_attn(ushort_t* smem, int u,
    const ushort_t* __restrict__ Qp, long long qns, long long qrs,
    const ushort_t* __restrict__ Prev, int pgrp, long long pstride,
    const ushort_t* __restrict__ Wkv, ushort_t* __restrict__ O)
{
    ushort_t* xp = smem;                                      // 64*264
    ushort_t (*qs)[72] = (ushort_t (*)[72])(smem + 64 * 264); // 64*72
    const int n = u >> 3, h = u & 7;
    const int tid = threadIdx.x;
    const int wave = tid >> 6, lane = tid & 63;
    const int lm = lane & 15, lq = lane >> 4;

    __syncthreads();   // previous phase/unit LDS reads done

    // load Q rows
    for (int idx = tid; idx < SEGL * 8; idx += 256) {
        int s = idx >> 3, d8 = (idx & 7) << 3;
        *(uint4*)&qs[s][d8] =
            *(const uint4*)(Qp + (long long)n * qns + (long long)s * qrs + h * DHEAD + d8);
    }

    // KV projection: wave 0/1 -> K cols 0-31/32-63; wave 2/3 -> V cols.
    const ushort_t* wbase = Wkv +
        (long long)((wave >> 1) * 512 + h * 64 + (wave & 1) * 32) * 512;
    ffrag kv[4][2];
#pragma unroll
    for (int i = 0; i < 4; ++i)
#pragma unroll
        for (int j = 0; j < 2; ++j) kv[i][j] = (ffrag){0.f, 0.f, 0.f, 0.f};

#pragma unroll
    for (int half = 0; half < 2; ++half) {
        __syncthreads();   // prior reads of xp done
        for (int idx = tid; idx < 64 * 33; idx += 256) {
            int s = idx / 33, c8 = (idx % 33) * 8;
            uint4 v = {0, 0, 0, 0};
            if (s < SEGL && c8 < 256) {
                long long r = (long long)n * SEGL + s;
                v = *(const uint4*)(Prev + (r / pgrp) * pstride
                                    + (r % pgrp) * DMODEL + half * 256 + c8);
            }
            *(uint4*)&xp[s * 264 + c8] = v;
        }
        __syncthreads();
#pragma unroll
        for (int k8 = 0; k8 < 8; ++k8) {
            const int kg = half * 256 + k8 * 32;
            bfrag bf[2], af[4];
#pragma unroll
            for (int j = 0; j < 2; ++j)
                bf[j] = *(const bfrag*)(wbase + (long long)(j * 16 + lm) * 512 + kg + lq * 8);
#pragma unroll
            for (int i = 0; i < 4; ++i)
                af[i] = *(const bfrag*)&xp[(i * 16 + lm) * 264 + k8 * 32 + lq * 8];
#pragma unroll
            for (int i = 0; i < 4; ++i)
#pragma unroll
                for (int j = 0; j < 2; ++j)
                    kv[i][j] = __builtin_amdgcn_mfma_f32_16x16x32_bf16(
                        af[i], bf[j], kv[i][j], 0, 0, 0);
        }
    }
    __syncthreads();   // all xp reads done before ks/vt overwrite
    ushort_t (*ks)[72] = (ushort_t(*)[72])&xp[0];
    ushort_t (*vt)[72] = (ushort_t(*)[72])&xp[64 * 72];
#pragma unroll
    for (int i = 0; i < 4; ++i)
#pragma unroll
        for (int j = 0; j < 2; ++j)
#pragma unroll
            for (int r = 0; r < 4; ++r) {
                int rowk = i * 16 + lq * 4 + r;
                int d = (wave & 1) * 32 + j * 16 + lm;
                ushort_t val = f2b(kv[i][j][r]);
                if (wave < 2) ks[rowk][d] = val;   // K[rowk][d]
                else          vt[d][rowk] = val;   // V^T[d][rowk]
            }
    __syncthreads();

    // QK^T
    ffrag sc[4];
#pragma unroll
    for (int nt = 0; nt < 4; ++nt) sc[nt] = (ffrag){0.f, 0.f, 0.f, 0.f};
#pragma unroll
    for (int kt = 0; kt < 2; ++kt) {
        bfrag a = *(const bfrag*)&qs[wave * 16 + lm][kt * 32 + lq * 8];
#pragma unroll
        for (int nt = 0; nt < 4; ++nt) {
            bfrag b = *(const bfrag*)&ks[nt * 16 + lm][kt * 32 + lq * 8];
            sc[nt] = __builtin_amdgcn_mfma_f32_16x16x32_bf16(a, b, sc[nt], 0, 0, 0);
        }
    }
    __syncthreads();

#pragma unroll
    for (int r = 0; r < 4; ++r) {
        float x[4];
        float mx = -1e30f;
#pragma unroll
        for (int nt = 0; nt < 4; ++nt) {
            int col = nt * 16 + lm;
            x[nt] = (col < SEGL) ? sc[nt][r] * 0.125f : -1e9f;
            mx = fmaxf(mx, x[nt]);
        }
        for (int off = 8; off; off >>= 1) mx = fmaxf(mx, __shfl_xor(mx, off));
        float e[4], se = 0.f;
#pragma unroll
        for (int nt = 0; nt < 4; ++nt) { e[nt] = __expf(x[nt] - mx); se += e[nt]; }
        for (int off = 8; off; off >>= 1) se += __shfl_xor(se, off);
        float inv = 1.f / se;
        int row = wave * 16 + lq * 4 + r;
#pragma unroll
        for (int nt = 0; nt < 4; ++nt)
            qs[row][nt * 16 + lm] = f2b(e[nt] * inv);
    }
    __syncthreads();

    // PV
    ffrag oc[4];
#pragma unroll
    for (int dt = 0; dt < 4; ++dt) oc[dt] = (ffrag){0.f, 0.f, 0.f, 0.f};
#pragma unroll
    for (int kt = 0; kt < 2; ++kt) {
        bfrag a = *(const bfrag*)&qs[wave * 16 + lm][kt * 32 + lq * 8];
#pragma unroll
        for (int dt = 0; dt < 4; ++dt) {
            bfrag b = *(const bfrag*)&vt[dt * 16 + lm][kt * 32 + lq * 8];
            oc[dt] = __builtin_amdgcn_mfma_f32_16x16x32_bf16(a, b, oc[dt], 0, 0, 0);
        }
    }
#pragma unroll
    for (int r = 0; r < 4; ++r) {
        int i = wave * 16 + lq * 4 + r;
        if (i < SEGL) {
            ushort_t* op = O + (long long)(n * SEGL + i) * DMODEL + h * DHEAD + lm;
#pragma unroll
            for (int dt = 0; dt < 4; ++dt)
                op[dt * 16] = f2b(oc[dt][r]);
        }
    }
}

// add+LN unit (== add_ln_k body, 4 rows/unit). No LDS, no barriers.
template<bool OUTF32>
__device__ void dev_add_ln(int u,
    const ushort_t* __restrict__ A, int agrp, long long astride,
    const ushort_t* __restrict__ Bv,
    const float* __restrict__ gamma, const float* __restrict__ beta,
    void* __restrict__ O, int ogrp, long long ostride, int M)
{
    const int wave = threadIdx.x >> 6, lane = threadIdx.x & 63;
    const int r = u * 4 + wave;
    if (r >= M) return;
    const ushort_t* a = A + (long long)(r / agrp) * astride + (long long)(r % agrp) * DMODEL;
    const ushort_t* b = Bv + (long long)r * DMODEL;
    float x[8];
    {
        uint4 a4 = *(const uint4*)(a + lane * 8);
        uint4 b4 = *(const uint4*)(b + lane * 8);
        const unsigned* aa = (const unsigned*)&a4;
        const unsigned* bb = (const unsigned*)&b4;
#pragma unroll
        for (int c = 0; c < 4; ++c) {
            union { unsigned u; float f; } alo, ahi, blo, bhi;
            alo.u = aa[c] << 16; ahi.u = aa[c] & 0xffff0000u;
            blo.u = bb[c] << 16; bhi.u = bb[c] & 0xffff0000u;
            x[2 * c]     = alo.f + blo.f;
            x[2 * c + 1] = ahi.f + bhi.f;
        }
    }
    float s = 0.f, s2 = 0.f;
#pragma unroll
    for (int i = 0; i < 8; ++i) { s += x[i]; s2 = fmaf(x[i], x[i], s2); }
    for (int off = 32; off; off >>= 1) {
        s += __shfl_xor(s, off);
        s2 += __shfl_xor(s2, off);
    }
    const float mean = s * (1.f / DMODEL);
    const float var = s2 * (1.f / DMODEL) - mean * mean;
    const float inv = rsqrtf(var + 1e-5f);
    float4 g0 = *(const float4*)(gamma + lane * 8);
    float4 g1 = *(const float4*)(gamma + lane * 8 + 4);
    float4 be0 = *(const float4*)(beta + lane * 8);
    float4 be1 = *(const float4*)(beta + lane * 8 + 4);
    float y[8];
    y[0] = (x[0] - mean) * inv * g0.x + be0.x;
    y[1] = (x[1] - mean) * inv * g0.y + be0.y;
    y[2] = (x[2] - mean) * inv * g0.z + be0.z;
    y[3] = (x[3] - mean) * inv * g0.w + be0.w;
    y[4] = (x[4] - mean) * inv * g1.x + be1.x;
    y[5] = (x[5] - mean) * inv * g1.y + be1.y;
    y[6] = (x[6] - mean) * inv * g1.z + be1.z;
    y[7] = (x[7] - mean) * inv * g1.w + be1.w;
    if (OUTF32) {
        float* o = (float*)O + (long long)(r / ogrp) * ostride + (long long)(r % ogrp) * DMODEL;
        *(float4*)(o + lane * 8) = *(float4*)&y[0];
        *(float4*)(o + lane * 8 + 4) = *(float4*)&y[4];
    } else {
        ushort_t* o = (ushort_t*)O + (long long)(r / ogrp) * ostride + (long long)(r % ogrp) * DMODEL;
        ushort_t ob[8];
#pragma unroll
        for (int i = 0; i < 8; ++i) ob[i] = f2b(y[i]);
        *(uint4*)(o + lane * 8) = *(const uint4*)ob;
    }
}

// Persistent phase-2: all 15 connection steps; 6 phases/step, grid barriers
// between. Launched as a PLAIN kernel; grid size chosen host-side so all
// blocks are co-resident (validated via the occupancy API).
__global__ __launch_bounds__(256, 2) void phase2_k(
    const ushort_t* __restrict__ ENC, const ushort_t* __restrict__ QALL,
    const ushort_t* __restrict__ cKV, const ushort_t* __restrict__ cWoT,
    const ushort_t* __restrict__ cF1T, const ushort_t* __restrict__ cF2T,
    const float* __restrict__ cG1, const float* __restrict__ cB1,
    const float* __restrict__ cG2, const float* __restrict__ cB2,
    ushort_t* __restrict__ BUF4, ushort_t* __restrict__ BUF0,
    ushort_t* __restrict__ BUF2, ushort_t* __restrict__ MID,
    ushort_t* __restrict__ OUTB, float* __restrict__ out,
    unsigned* __restrict__ bar)
{
    __shared__ ushort_t smem[21504];   // 43008 B: max(cross_attn, gemm64)
    const int nblk = gridDim.x;
    const int Ms = NB * SEGL;                       // 3200
    const long long SEQROW = (long long)NT * SEGL * DMODEL;  // 409600
    unsigned target = 0;

    for (int t = 1; t < NT; ++t) {
        const ushort_t* prevA; int pg; long long ps;
        if (t == 1) { prevA = ENC;  pg = SEGL; ps = SEQROW; }
        else        { prevA = OUTB; pg = Ms;   ps = 0; }
        const ushort_t* currA = ENC + (long long)t * SEGL * DMODEL;

        // A: fused KV-projection + cross-attention -> BUF4 (512 units)
        for (int u = blockIdx.x; u < NB * NHEAD; u += nblk)
            dev_cross_attn(smem, u,
                           QALL + (long long)(t - 1) * 25600, 750LL * 512, 512,
                           prevA, pg, ps, cKV, BUF4);
        target += nblk; gbar(bar, target);

        // B: Wo GEMM: 3200x512x512 -> BUF0 (400 units)
        for (int u = blockIdx.x; u < (512 / 64) * (Ms / 64); u += nblk)
            dev_gemm64(smem, u, BUF4, Ms, 0, cWoT, BUF0, Ms, 512, 512, 0);
        target += nblk; gbar(bar, target);

        // C: LN(curr + BUF0) -> BUF2 (800 units)
        for (int u = blockIdx.x; u < Ms / 4; u += nblk)
            dev_add_ln<false>(u, currA, SEGL, SEQROW, BUF0, cG1, cB1,
                              BUF2, Ms, 0, Ms);
        target += nblk; gbar(bar, target);

        // D: F1 GEMM + relu: 3200x2048x512 -> MID (1600 units)
        for (int u = blockIdx.x; u < (2048 / 64) * (Ms / 64); u += nblk)
            dev_gemm64(smem, u, BUF2, Ms, 0, cF1T, MID, Ms, 2048, 512, 1);
        target += nblk; gbar(bar, target);

        // E: F2 GEMM: 3200x512x2048 -> BUF0 (400 units)
        for (int u = blockIdx.x; u < (512 / 64) * (Ms / 64); u += nblk)
            dev_gemm64(smem, u, MID, Ms, 0, cF2T, BUF0, Ms, 512, 2048, 0);
        target += nblk; gbar(bar, target);

        // F: LN(BUF2 + BUF0) -> OUTB (or f32 out on last step)
        if (t == NT - 1) {
            for (int u = blockIdx.x; u < Ms / 4; u += nblk)
                dev_add_ln<true>(u, BUF2, Ms, 0, BUF0, cG2, cB2,
                                 out, Ms, 0, Ms);
        } else {
            for (int u = blockIdx.x; u < Ms / 4; u += nblk)
                dev_add_ln<false>(u, BUF2, Ms, 0, BUF0, cG2, cB2,
                                  OUTB, Ms, 0, Ms);
        }
        target += nblk; gbar(bar, target);
    }
}

// ---------------------------------------------------------------------------
extern "C" void kernel_launch(void* const* d_in, const int* in_sizes, int n_in,
                              void* d_out, int out_size, void* d_ws, size_t ws_size,
                              hipStream_t stream)
{
    const float* seqs = (const float*)d_in[0];
    const int*   ends = (const int*)d_in[1];
    const float* eG1 = (const float*)d_in[7],  *eB1 = (const float*)d_in[8];
    const float* eG2 = (const float*)d_in[11], *eB2 = (const float*)d_in[12];
    const float* cG1 = (const float*)d_in[17], *cB1 = (const float*)d_in[18];
    const float* cG2 = (const float*)d_in[21], *cB2 = (const float*)d_in[22];
    float* out = (float*)d_out;

    const int G = (ws_size >= (size_t)470000000) ? 8 : 4;
    const long long CH = 1638400LL * G;

    ushort_t* ws = (ushort_t*)d_ws;
    const long long SEQROW = (long long)NT * SEGL * DMODEL;    // 409600
    ushort_t* SEQB = ws;
    ushort_t* WT   = SEQB + 26214400LL;
    ushort_t* ENC  = WT   + 6553600LL;
    ushort_t* BUF0 = ENC  + 26214400LL;
    ushort_t* QKV  = BUF0 + CH;
    ushort_t* BUF4 = QKV  + 3 * CH;
    ushort_t* BUF1 = BUF4 + CH;
    ushort_t* BUF2 = BUF1 + CH;
    ushort_t* MID  = BUF2 + CH;
    ushort_t* OUTB = MID  + 4 * CH;
    ushort_t* QALL = OUTB + 1638400LL;
    int*      lens = (int*)(QALL + 24576000LL);
    unsigned* bar  = (unsigned*)(lens + 1024);

    const ushort_t* eWinT = WT + 0;
    const ushort_t* WQKVe = WT + 262144;      // 1536 x 512
    const ushort_t* eWoT  = WT + 1048576;
    const ushort_t* eF1T  = WT + 1310720;     // 2048 x 512
    const ushort_t* eF2T  = WT + 2359296;     // 512 x 2048
    const ushort_t* cWqT  = WT + 3407872;
    const ushort_t* cKV   = WT + 3670016;     // 1024 x 512
    const ushort_t* cWoT  = WT + 4194304;
    const ushort_t* cF1T  = WT + 4456448;
    const ushort_t* cF2T  = WT + 5505024;

    struct WMap { int src; long long dst; int K, N; };
    const WMap wm[13] = {
        {2,  0,       512, 512},
        {3,  262144,  512, 512},
        {4,  524288,  512, 512},
        {5,  786432,  512, 512},
        {6,  1048576, 512, 512},
        {9,  1310720, 512, 2048},
        {10, 2359296, 2048, 512},
        {13, 3407872, 512, 512},
        {14, 3670016, 512, 512},
        {15, 3932160, 512, 512},
        {16, 4194304, 512, 512},
        {19, 4456448, 512, 2048},
        {20, 5505024, 2048, 512},
    };

    cvt_k<<<12800, 256, 0, stream>>>(seqs, SEQB, 26214400LL);
    for (int w = 0; w < 13; ++w) {
        dim3 g(wm[w].N / 32, wm[w].K / 32);
        wtrans_k<<<g, 256, 0, stream>>>((const float*)d_in[wm[w].src],
                                        WT + wm[w].dst, wm[w].K, wm[w].N);
    }
    lens_k<<<4, 256, 0, stream>>>(ends, lens, bar);

    auto gemmL = [&](const ushort_t* A, int agrp, long long astr, const ushort_t* Bt,
                     ushort_t* C, int M, int N, int K, int relu) {
        dim3 g(N / 128, M / 128);
        mfma_gemm<128, 128, 2, 2><<<g, 256, 0, stream>>>(A, agrp, astr, Bt, C, M, N, K, relu);
    };

    // ---------------- Phase 1: all encoders, chunks of G segments ----------
    const int Mc = NB * G * SEGL;
    for (int c = 0; c < NT / G; ++c) {
        const int t0 = c * G;
        const ushort_t* Abase = SEQB + (long long)t0 * SEGL * DMODEL;
        ushort_t* ENCc = ENC + (long long)t0 * SEGL * DMODEL;
        gemmL(Abase, G * SEGL, SEQROW, eWinT, BUF0, Mc, 512, 512, 0);
        gemmL(BUF0, Mc, 0, WQKVe, QKV, Mc, 1536, 512, 0);
        attn_mfma_k<<<NB * G * NHEAD, 256, 0, stream>>>(
            QKV, 50LL * 1536, 1536, QKV + 512, QKV + 1024, 50LL * 1536, 1536,
            BUF4, lens, G, t0);
        gemmL(BUF4, Mc, 0, eWoT, BUF1, Mc, 512, 512, 0);
        add_ln_k<false><<<Mc / 4, 256, 0, stream>>>(BUF0, Mc, 0, BUF1, eG1, eB1,
                                                    BUF2, Mc, 0, Mc);
        gemmL(BUF2, Mc, 0, eF1T, MID, Mc, 2048, 512, 1);
        gemmL(MID, Mc, 0, eF2T, BUF1, Mc, 512, 2048, 0);
        add_ln_k<false><<<Mc / 4, 256, 0, stream>>>(BUF2, Mc, 0, BUF1, eG2, eB2,
                                                    ENCc, G * SEGL, SEQROW, Mc);
    }

    // Batched Q projections for ALL phase-2 steps
    gemmL(ENC + 25600, 750, SEQROW, cWqT, QALL, 48000, 512, 512, 0);

    // ---------------- Phase 2: single persistent kernel (plain launch) -----
    {
        // Co-residency check: grid must not exceed occupancy * numCU (256).
        static int grid = 0;
        if (grid == 0) {
            int occ = 0;
            if (hipOccupancyMaxActiveBlocksPerMultiprocessor(
                    &occ, phase2_k, 256, 0) != hipSuccess || occ < 1)
                occ = 1;
            grid = (occ >= 2) ? 512 : 256;
        }
        phase2_k<<<grid, 256, 0, stream>>>(
            ENC, QALL, cKV, cWoT, cF1T, cF2T,
            cG1, cB1, cG2, cB2,
            BUF4, BUF0, BUF2, MID, OUTB, out, bar);
    }
}

// Round 3
// 4596.565 us; speedup vs baseline: 1.1631x; 1.1631x over previous
//
#include <hip/hip_runtime.h>

// RecurrentTransformerEncoder on MI355X — round 11: fix the grid-barrier
// contention. Round 10's gbar had 512 atomicAdds + 512 fast-polling spinners
// on ONE cache line -> ~65us/barrier (phase2_k 5818us, MfmaUtil 2%). New
// barrier: two-level arrival (8 padded group counters -> master) + separate
// release-flag line polled with s_sleep(32) backoff. Everything else is
// byte-identical to the passing round-10 kernel.
// B=64, T=16, SEG=50, E=D=512, H=8, DH=64, F=2048.

#define NB   64
#define NT   16
#define SEGL 50
#define DMODEL 512
#define DFF  2048
#define NHEAD 8
#define DHEAD 64

typedef unsigned short ushort_t;
typedef __attribute__((ext_vector_type(8))) short bfrag;   // 8 bf16 (4 VGPRs)
typedef __attribute__((ext_vector_type(4))) float ffrag;   // 4 fp32 acc

__device__ __forceinline__ ushort_t f2b(float x) {
    union { float f; unsigned u; } c; c.f = x;
    unsigned r = c.u + 0x7fffu + ((c.u >> 16) & 1u);
    return (ushort_t)(r >> 16);
}

#define GLOAD_LDS16(g, l) __builtin_amdgcn_global_load_lds( \
    (const __attribute__((address_space(1))) void*)(g),      \
    (__attribute__((address_space(3))) void*)(l), 16, 0, 0)

// ---------------------------------------------------------------------------
// MFMA GEMM (LDS-staged, BK=64 dbuf): C = relu?(A @ Bt^T), bf16.
// A rows remapped: row m at A + (m/agrp)*astride + (m%agrp)*K.
// Used for the big phase-1 GEMMs (128x128 tiles).
// ---------------------------------------------------------------------------
template<int BM, int BN, int WROWS, int WCOLS>
__global__ __launch_bounds__(256) void mfma_gemm(
    const ushort_t* __restrict__ A, int agrp, long long astride,
    const ushort_t* __restrict__ Bt, ushort_t* __restrict__ C,
    int M, int N, int K, int relu)
{
    constexpr int WM = BM / WROWS, WN = BN / WCOLS;
    constexpr int SM = WM / 16, SN = WN / 16;
    constexpr int NSUBA = BM / 16, NSUBB = BN / 16;
    constexpr int NSUB = NSUBA + NSUBB;
    constexpr int NINST = NSUB * 2;
    constexpr int IPW = NINST / 4;
    constexpr int BUFS = NSUB * 1024;
    constexpr int EST = WN + 8;
    constexpr int LDS_KLOOP = 2 * BUFS;
    constexpr int LDS_EPI   = 4 * WM * EST;
    constexpr int LDS_SZ = LDS_KLOOP > LDS_EPI ? LDS_KLOOP : LDS_EPI;
    __shared__ ushort_t lds[LDS_SZ];

    const int tid = threadIdx.x;
    const int wave = tid >> 6, lane = tid & 63;
    const int wrow = wave / WCOLS, wcol = wave % WCOLS;
    const int bm = blockIdx.y * BM, bn = blockIdx.x * BN;
    const int lm = lane & 15, lq = lane >> 4;

    ffrag acc[SM][SN];
#pragma unroll
    for (int i = 0; i < SM; ++i)
#pragma unroll
        for (int j = 0; j < SN; ++j) acc[i][j] = (ffrag){0.f, 0.f, 0.f, 0.f};

    const ushort_t* gptr[IPW];
    int loff[IPW];
#pragma unroll
    for (int e = 0; e < IPW; ++e) {
        int g = wave * IPW + e;
        int s = g >> 1, h = g & 1;
        if (s < NSUBA) {
            int m = bm + s * 16 + lm;
            gptr[e] = A + (long long)(m / agrp) * astride
                        + (long long)(m % agrp) * K + h * 32 + lq * 8;
        } else {
            int n = bn + (s - NSUBA) * 16 + lm;
            gptr[e] = Bt + (long long)n * K + h * 32 + lq * 8;
        }
        loff[e] = s * 1024 + h * 512;
    }

#pragma unroll
    for (int e = 0; e < IPW; ++e)
        GLOAD_LDS16(gptr[e], &lds[loff[e]]);

    const int nk = K >> 6;
    for (int kk = 0; kk < nk; ++kk) {
        __syncthreads();
        if (kk + 1 < nk) {
            const int koff = (kk + 1) << 6;
            const int nb = (kk + 1) & 1;
#pragma unroll
            for (int e = 0; e < IPW; ++e)
                GLOAD_LDS16(gptr[e] + koff, &lds[nb * BUFS + loff[e]]);
        }
        const ushort_t* lb = &lds[(kk & 1) * BUFS];
#pragma unroll
        for (int h = 0; h < 2; ++h) {
            bfrag af[SM], bfg[SN];
#pragma unroll
            for (int i = 0; i < SM; ++i)
                af[i] = *(const bfrag*)&lb[(wrow * SM + i) * 1024 + h * 512 + lane * 8];
#pragma unroll
            for (int j = 0; j < SN; ++j)
                bfg[j] = *(const bfrag*)&lb[(NSUBA + wcol * SN + j) * 1024 + h * 512 + lane * 8];
#pragma unroll
            for (int i = 0; i < SM; ++i)
#pragma unroll
                for (int j = 0; j < SN; ++j)
                    acc[i][j] = __builtin_amdgcn_mfma_f32_16x16x32_bf16(
                        af[i], bfg[j], acc[i][j], 0, 0, 0);
        }
    }

    __syncthreads();
    ushort_t* ep = &lds[wave * WM * EST];
#pragma unroll
    for (int i = 0; i < SM; ++i)
#pragma unroll
        for (int j = 0; j < SN; ++j)
#pragma unroll
            for (int r = 0; r < 4; ++r) {
                int row = i * 16 + lq * 4 + r;
                int col = j * 16 + lm;
                float v = acc[i][j][r];
                if (relu) v = fmaxf(v, 0.f);
                ep[row * EST + col] = f2b(v);
            }
    constexpr int CPR = WN / 8;
    constexpr int RPI = 64 / CPR;
    const int lrow = lane / CPR, lcol = (lane % CPR) * 8;
#pragma unroll
    for (int it = 0; it < WM / RPI; ++it) {
        int row = it * RPI + lrow;
        uint4 v = *(const uint4*)&ep[row * EST + lcol];
        long long grow = bm + wrow * WM + row;
        int gcol = bn + wcol * WN + lcol;
        *(uint4*)&C[grow * N + gcol] = v;
    }
}

// ---------------------------------------------------------------------------
__global__ __launch_bounds__(256) void wtrans_k(
    const float* __restrict__ W, ushort_t* __restrict__ Wt, int K, int N)
{
    __shared__ float t[32][33];
    const int bk = blockIdx.y * 32, bn = blockIdx.x * 32;
    const int tx = threadIdx.x & 31, ty = threadIdx.x >> 5;
    for (int i = ty; i < 32; i += 8)
        t[i][tx] = W[(long long)(bk + i) * N + bn + tx];
    __syncthreads();
    for (int i = ty; i < 32; i += 8)
        Wt[(long long)(bn + i) * K + bk + tx] = f2b(t[tx][i]);
}

__global__ __launch_bounds__(256) void cvt_k(
    const float* __restrict__ in, ushort_t* __restrict__ out, long long n)
{
    long long i = ((long long)blockIdx.x * 256 + threadIdx.x) * 8;
    if (i >= n) return;
    float4 a = *(const float4*)(in + i);
    float4 b = *(const float4*)(in + i + 4);
    ushort_t o[8] = {f2b(a.x), f2b(a.y), f2b(a.z), f2b(a.w),
                     f2b(b.x), f2b(b.y), f2b(b.z), f2b(b.w)};
    *(uint4*)(out + i) = *(const uint4*)o;
}

// ---------------------------------------------------------------------------
// Phase-1 MFMA attention, one (sequence n, head h) per block. S=50->64, D=64.
// ---------------------------------------------------------------------------
__global__ __launch_bounds__(256) void attn_mfma_k(
    const ushort_t* __restrict__ Q, long long qns, long long qrs,
    const ushort_t* __restrict__ K, const ushort_t* __restrict__ V,
    long long kns, long long kvrs,
    ushort_t* __restrict__ O,
    const int* __restrict__ lens, int G, int t0)
{
    __shared__ ushort_t qs[64][72];   // Q, then P
    __shared__ ushort_t ks[64][72];
    __shared__ ushort_t vt[64][72];   // V^T
    const int n = blockIdx.x >> 3, h = blockIdx.x & 7;
    const int tid = threadIdx.x;
    const int wave = tid >> 6, lane = tid & 63;
    const int lm = lane & 15, lq = lane >> 4;
    int len = SEGL;
    if (lens) {
        int b = n / G, t = t0 + (n % G);
        len = lens[b * NT + t];
        if (len > SEGL) len = SEGL;
    }
    {
        uint4 z = {0, 0, 0, 0};
        uint4* vz = (uint4*)&vt[0][0];
        for (int i = tid; i < 64 * 72 / 8; i += 256) vz[i] = z;
    }
    __syncthreads();
    for (int idx = tid; idx < SEGL * 8; idx += 256) {
        int s = idx >> 3, d8 = (idx & 7) << 3;
        const ushort_t* qp = Q + (long long)n * qns + (long long)s * qrs + h * DHEAD + d8;
        const ushort_t* kp = K + (long long)n * kns + (long long)s * kvrs + h * DHEAD + d8;
        const ushort_t* vp = V + (long long)n * kns + (long long)s * kvrs + h * DHEAD + d8;
        *(uint4*)&qs[s][d8] = *(const uint4*)qp;
        *(uint4*)&ks[s][d8] = *(const uint4*)kp;
        uint4 v4 = *(const uint4*)vp;
        const ushort_t* vv = (const ushort_t*)&v4;
#pragma unroll
        for (int u = 0; u < 8; ++u) vt[d8 + u][s] = vv[u];
    }
    __syncthreads();

    ffrag sc[4];
#pragma unroll
    for (int nt = 0; nt < 4; ++nt) sc[nt] = (ffrag){0.f, 0.f, 0.f, 0.f};
#pragma unroll
    for (int kt = 0; kt < 2; ++kt) {
        bfrag a = *(const bfrag*)&qs[wave * 16 + lm][kt * 32 + lq * 8];
#pragma unroll
        for (int nt = 0; nt < 4; ++nt) {
            bfrag b = *(const bfrag*)&ks[nt * 16 + lm][kt * 32 + lq * 8];
            sc[nt] = __builtin_amdgcn_mfma_f32_16x16x32_bf16(a, b, sc[nt], 0, 0, 0);
        }
    }
    __syncthreads();

#pragma unroll
    for (int r = 0; r < 4; ++r) {
        float x[4];
        float mx = -1e30f;
#pragma unroll
        for (int nt = 0; nt < 4; ++nt) {
            int col = nt * 16 + lm;
            x[nt] = (col < len) ? sc[nt][r] * 0.125f : -1e9f;
            mx = fmaxf(mx, x[nt]);
        }
        for (int off = 8; off; off >>= 1) mx = fmaxf(mx, __shfl_xor(mx, off));
        float e[4], se = 0.f;
#pragma unroll
        for (int nt = 0; nt < 4; ++nt) { e[nt] = __expf(x[nt] - mx); se += e[nt]; }
        for (int off = 8; off; off >>= 1) se += __shfl_xor(se, off);
        float inv = 1.f / se;
        int row = wave * 16 + lq * 4 + r;
#pragma unroll
        for (int nt = 0; nt < 4; ++nt)
            qs[row][nt * 16 + lm] = f2b(e[nt] * inv);
    }
    __syncthreads();

    ffrag oc[4];
#pragma unroll
    for (int dt = 0; dt < 4; ++dt) oc[dt] = (ffrag){0.f, 0.f, 0.f, 0.f};
#pragma unroll
    for (int kt = 0; kt < 2; ++kt) {
        bfrag a = *(const bfrag*)&qs[wave * 16 + lm][kt * 32 + lq * 8];
#pragma unroll
        for (int dt = 0; dt < 4; ++dt) {
            bfrag b = *(const bfrag*)&vt[dt * 16 + lm][kt * 32 + lq * 8];
            oc[dt] = __builtin_amdgcn_mfma_f32_16x16x32_bf16(a, b, oc[dt], 0, 0, 0);
        }
    }
#pragma unroll
    for (int r = 0; r < 4; ++r) {
        int i = wave * 16 + lq * 4 + r;
        if (i < SEGL) {
            ushort_t* op = O + (long long)(n * SEGL + i) * DMODEL + h * DHEAD + lm;
#pragma unroll
            for (int dt = 0; dt < 4; ++dt)
                op[dt * 16] = f2b(oc[dt][r]);
        }
    }
}

// ---------------------------------------------------------------------------
// out = LN(a + b)*gamma + beta, rows of 512, bf16 in, bf16/fp32 out. (phase 1)
// ---------------------------------------------------------------------------
template<bool OUTF32>
__global__ __launch_bounds__(256) void add_ln_k(
    const ushort_t* __restrict__ A, int agrp, long long astride,
    const ushort_t* __restrict__ Bv,
    const float* __restrict__ gamma, const float* __restrict__ beta,
    void* __restrict__ O, int ogrp, long long ostride, int M)
{
    const int wave = threadIdx.x >> 6, lane = threadIdx.x & 63;
    const int r = blockIdx.x * 4 + wave;
    if (r >= M) return;
    const ushort_t* a = A + (long long)(r / agrp) * astride + (long long)(r % agrp) * DMODEL;
    const ushort_t* b = Bv + (long long)r * DMODEL;
    float x[8];
    {
        uint4 a4 = *(const uint4*)(a + lane * 8);
        uint4 b4 = *(const uint4*)(b + lane * 8);
        const unsigned* aa = (const unsigned*)&a4;
        const unsigned* bb = (const unsigned*)&b4;
#pragma unroll
        for (int c = 0; c < 4; ++c) {
            union { unsigned u; float f; } alo, ahi, blo, bhi;
            alo.u = aa[c] << 16; ahi.u = aa[c] & 0xffff0000u;
            blo.u = bb[c] << 16; bhi.u = bb[c] & 0xffff0000u;
            x[2 * c]     = alo.f + blo.f;
            x[2 * c + 1] = ahi.f + bhi.f;
        }
    }
    float s = 0.f, s2 = 0.f;
#pragma unroll
    for (int i = 0; i < 8; ++i) { s += x[i]; s2 = fmaf(x[i], x[i], s2); }
    for (int off = 32; off; off >>= 1) {
        s += __shfl_xor(s, off);
        s2 += __shfl_xor(s2, off);
    }
    const float mean = s * (1.f / DMODEL);
    const float var = s2 * (1.f / DMODEL) - mean * mean;
    const float inv = rsqrtf(var + 1e-5f);
    float4 g0 = *(const float4*)(gamma + lane * 8);
    float4 g1 = *(const float4*)(gamma + lane * 8 + 4);
    float4 be0 = *(const float4*)(beta + lane * 8);
    float4 be1 = *(const float4*)(beta + lane * 8 + 4);
    float y[8];
    y[0] = (x[0] - mean) * inv * g0.x + be0.x;
    y[1] = (x[1] - mean) * inv * g0.y + be0.y;
    y[2] = (x[2] - mean) * inv * g0.z + be0.z;
    y[3] = (x[3] - mean) * inv * g0.w + be0.w;
    y[4] = (x[4] - mean) * inv * g1.x + be1.x;
    y[5] = (x[5] - mean) * inv * g1.y + be1.y;
    y[6] = (x[6] - mean) * inv * g1.z + be1.z;
    y[7] = (x[7] - mean) * inv * g1.w + be1.w;
    if (OUTF32) {
        float* o = (float*)O + (long long)(r / ogrp) * ostride + (long long)(r % ogrp) * DMODEL;
        *(float4*)(o + lane * 8) = *(float4*)&y[0];
        *(float4*)(o + lane * 8 + 4) = *(float4*)&y[4];
    } else {
        ushort_t* o = (ushort_t*)O + (long long)(r / ogrp) * ostride + (long long)(r % ogrp) * DMODEL;
        ushort_t ob[8];
#pragma unroll
        for (int i = 0; i < 8; ++i) ob[i] = f2b(y[i]);
        *(uint4*)(o + lane * 8) = *(const uint4*)ob;
    }
}

// lens + barrier-state reset (kernel node -> runs on every graph replay, in
// stream order before phase2_k). Barrier region = 512 uints.
__global__ void lens_k(const int* __restrict__ ends, int* __restrict__ lens,
                       unsigned* __restrict__ bar)
{
    int i = blockIdx.x * 256 + threadIdx.x;
    if (i < 512) bar[i] = 0;
    if (i >= NB * NT) return;
    int t = i & (NT - 1);
    int prev = t ? ends[i - 1] : 0;
    int l = ends[i] - prev;
    if (l > SEGL) l = SEGL;
    lens[i] = l;
}

// ===========================================================================
// Persistent phase-2: device-side ports of the per-step kernels.
// ===========================================================================

// Two-level grid barrier (contention-safe):
//   arrival : 8 group counters, 128B apart (g = blockIdx.x & 7, gsz adds each,
//             8 lines in parallel) -> last of group adds to master counter ->
//             last master stores release = p on ITS OWN line.
//   wait    : poll ONLY the release line (written once/barrier) with
//             s_sleep(32) (~0.85us) backoff. RMW lines see no read traffic.
// Counters are monotonic; lens_k zeroes them each launch. Bounded spin turns
// a co-residency failure into a visible wrong answer instead of a hang.
// Layout (uints): group g at [g*32]; master at [256]; release at [288].
__device__ __forceinline__ void gbar(unsigned* bar, int p, int gsz)
{
    __syncthreads();                       // all waves drain their mem ops
    if (threadIdx.x == 0) {
        __threadfence();                   // release: make writes visible
        const int g = blockIdx.x & 7;
        unsigned old = __hip_atomic_fetch_add(&bar[g * 32], 1u,
                           __ATOMIC_RELAXED, __HIP_MEMORY_SCOPE_AGENT);
        if (old == (unsigned)(p * gsz - 1)) {          // last in group
            unsigned om = __hip_atomic_fetch_add(&bar[256], 1u,
                              __ATOMIC_RELAXED, __HIP_MEMORY_SCOPE_AGENT);
            if (om == (unsigned)(p * 8 - 1))           // last group
                __hip_atomic_store(&bar[288], (unsigned)p,
                                   __ATOMIC_RELEASE, __HIP_MEMORY_SCOPE_AGENT);
        }
        int spins = 0;
        while (__hip_atomic_load(&bar[288], __ATOMIC_RELAXED,
                                 __HIP_MEMORY_SCOPE_AGENT) < (unsigned)p) {
            __builtin_amdgcn_s_sleep(32);
            if (++spins > (1 << 18)) break;            // escape hatch
        }
        __threadfence();                   // acquire
    }
    __syncthreads();
}

// 64x64-tile GEMM unit (== mfma_gemm<64,64,2,2> body), u = by*(N/64)+bx.
// Uses smem[0 .. 16384) ushorts. __syncthreads at entry guards LDS reuse.
__device__ void dev_gemm64(ushort_t* lds, int u,
    const ushort_t* __restrict__ A, int agrp, long long astride,
    const ushort_t* __restrict__ Bt, ushort_t* __restrict__ C,
    int M, int N, int K, int relu)
{
    const int tid = threadIdx.x;
    const int wave = tid >> 6, lane = tid & 63;
    const int wrow = wave >> 1, wcol = wave & 1;
    const int nbx = N >> 6;
    const int bm = (u / nbx) << 6, bn = (u % nbx) << 6;
    const int lm = lane & 15, lq = lane >> 4;

    __syncthreads();   // previous unit's LDS reads done before we overwrite

    ffrag acc[2][2];
#pragma unroll
    for (int i = 0; i < 2; ++i)
#pragma unroll
        for (int j = 0; j < 2; ++j) acc[i][j] = (ffrag){0.f, 0.f, 0.f, 0.f};

    const ushort_t* gptr[4];
    int loff[4];
#pragma unroll
    for (int e = 0; e < 4; ++e) {
        int g = wave * 4 + e;
        int s = g >> 1, h = g & 1;
        if (s < 4) {
            int m = bm + s * 16 + lm;
            gptr[e] = A + (long long)(m / agrp) * astride
                        + (long long)(m % agrp) * K + h * 32 + lq * 8;
        } else {
            int n = bn + (s - 4) * 16 + lm;
            gptr[e] = Bt + (long long)n * K + h * 32 + lq * 8;
        }
        loff[e] = s * 1024 + h * 512;
    }

#pragma unroll
    for (int e = 0; e < 4; ++e)
        GLOAD_LDS16(gptr[e], &lds[loff[e]]);

    const int nk = K >> 6;
    for (int kk = 0; kk < nk; ++kk) {
        __syncthreads();
        if (kk + 1 < nk) {
            const int koff = (kk + 1) << 6;
            const int nb = (kk + 1) & 1;
#pragma unroll
            for (int e = 0; e < 4; ++e)
                GLOAD_LDS16(gptr[e] + koff, &lds[nb * 8192 + loff[e]]);
        }
        const ushort_t* lb = &lds[(kk & 1) * 8192];
#pragma unroll
        for (int h = 0; h < 2; ++h) {
            bfrag af[2], bfg[2];
#pragma unroll
            for (int i = 0; i < 2; ++i)
                af[i] = *(const bfrag*)&lb[(wrow * 2 + i) * 1024 + h * 512 + lane * 8];
#pragma unroll
            for (int j = 0; j < 2; ++j)
                bfg[j] = *(const bfrag*)&lb[(4 + wcol * 2 + j) * 1024 + h * 512 + lane * 8];
#pragma unroll
            for (int i = 0; i < 2; ++i)
#pragma unroll
                for (int j = 0; j < 2; ++j)
                    acc[i][j] = __builtin_amdgcn_mfma_f32_16x16x32_bf16(
                        af[i], bfg[j], acc[i][j], 0, 0, 0);
        }
    }

    __syncthreads();
    ushort_t* ep = &lds[wave * 32 * 40];
#pragma unroll
    for (int i = 0; i < 2; ++i)
#pragma unroll
        for (int j = 0; j < 2; ++j)
#pragma unroll
            for (int r = 0; r < 4; ++r) {
                int row = i * 16 + lq * 4 + r;
                int col = j * 16 + lm;
                float v = acc[i][j][r];
                if (relu) v = fmaxf(v, 0.f);
                ep[row * 40 + col] = f2b(v);
            }
    // same-wave LDS write->read: ordered, no barrier needed
    const int lrow = lane >> 2, lcol = (lane & 3) * 8;
#pragma unroll
    for (int it = 0; it < 2; ++it) {
        int row = it * 16 + lrow;
        uint4 v = *(const uint4*)&ep[row * 40 + lcol];
        long long grow = bm + wrow * 32 + row;
        int gcol = bn + wcol * 32 + lcol;
        *(uint4*)&C[grow * N + gcol] = v;
    }
}

// Fused KV-projection + cross-attention unit (== cross_attn_k body).
// Uses smem[0 .. 21504) ushorts: xp = 64*264, qs = 64*72.
__device__ void dev_cross_attn(ushort_t* smem, int u,
    const ushort_t* __restrict__ Qp, long long qns, long long qrs,
    const ushort_t* __restrict__ Prev, int pgrp, long long pstride,
    const ushort_t* __restrict__ Wkv, ushort_t* __restrict__ O)
{
    ushort_t* xp = smem;                                      // 64*264
    ushort_t (*qs)[72] = (ushort_t (*)[72])(smem + 64 * 264); // 64*72
    const int n = u >> 3, h = u & 7;
    const int tid = threadIdx.x;
    const int wave = tid >> 6, lane = tid & 63;
    const int lm = lane & 15, lq = lane >> 4;

    __syncthreads();   // previous phase/unit LDS reads done

    // load Q rows
    for (int idx = tid; idx < SEGL * 8; idx += 256) {
        int s = idx >> 3, d8 = (idx & 7) << 3;
        *(uint4*)&qs[s][d8] =
            *(const uint4*)(Qp + (long long)n * qns + (long long)s * qrs + h * DHEAD + d8);
    }

    // KV projection: wave 0/1 -> K cols 0-31/32-63; wave 2/3 -> V cols.
    const ushort_t* wbase = Wkv +
        (long long)((wave >> 1) * 512 + h * 64 + (wave & 1) * 32) * 512;
    ffrag kv[4][2];
#pragma unroll
    for (int i = 0; i < 4; ++i)
#pragma unroll
        for (int j = 0; j < 2; ++j) kv[i][j] = (ffrag){0.f, 0.f, 0.f, 0.f};

#pragma unroll
    for (int half = 0; half < 2; ++half) {
        __syncthreads();   // prior reads of xp done
        for (int idx = tid; idx < 64 * 33; idx += 256) {
            int s = idx / 33, c8 = (idx % 33) * 8;
            uint4 v = {0, 0, 0, 0};
            if (s < SEGL && c8 < 256) {
                long long r = (long long)n * SEGL + s;
                v = *(const uint4*)(Prev + (r / pgrp) * pstride
                                    + (r % pgrp) * DMODEL + half * 256 + c8);
            }
            *(uint4*)&xp[s * 264 + c8] = v;
        }
        __syncthreads();
#pragma unroll
        for (int k8 = 0; k8 < 8; ++k8) {
            const int kg = half * 256 + k8 * 32;
            bfrag bf[2], af[4];
#pragma unroll
            for (int j = 0; j < 2; ++j)
                bf[j] = *(const bfrag*)(wbase + (long long)(j * 16 + lm) * 512 + kg + lq * 8);
#pragma unroll
            for (int i = 0; i < 4; ++i)
                af[i] = *(const bfrag*)&xp[(i * 16 + lm) * 264 + k8 * 32 + lq * 8];
#pragma unroll
            for (int i = 0; i < 4; ++i)
#pragma unroll
                for (int j = 0; j < 2; ++j)
                    kv[i][j] = __builtin_amdgcn_mfma_f32_16x16x32_bf16(
                        af[i], bf[j], kv[i][j], 0, 0, 0);
        }
    }
    __syncthreads();   // all xp reads done before ks/vt overwrite
    ushort_t (*ks)[72] = (ushort_t(*)[72])&xp[0];
    ushort_t (*vt)[72] = (ushort_t(*)[72])&xp[64 * 72];
#pragma unroll
    for (int i = 0; i < 4; ++i)
#pragma unroll
        for (int j = 0; j < 2; ++j)
#pragma unroll
            for (int r = 0; r < 4; ++r) {
                int rowk = i * 16 + lq * 4 + r;
                int d = (wave & 1) * 32 + j * 16 + lm;
                ushort_t val = f2b(kv[i][j][r]);
                if (wave < 2) ks[rowk][d] = val;   // K[rowk][d]
                else          vt[d][rowk] = val;   // V^T[d][rowk]
            }
    __syncthreads();

    // QK^T
    ffrag sc[4];
#pragma unroll
    for (int nt = 0; nt < 4; ++nt) sc[nt] = (ffrag){0.f, 0.f, 0.f, 0.f};
#pragma unroll
    for (int kt = 0; kt < 2; ++kt) {
        bfrag a = *(const bfrag*)&qs[wave * 16 + lm][kt * 32 + lq * 8];
#pragma unroll
        for (int nt = 0; nt < 4; ++nt) {
            bfrag b = *(const bfrag*)&ks[nt * 16 + lm][kt * 32 + lq * 8];
            sc[nt] = __builtin_amdgcn_mfma_f32_16x16x32_bf16(a, b, sc[nt], 0, 0, 0);
        }
    }
    __syncthreads();

#pragma unroll
    for (int r = 0; r < 4; ++r) {
        float x[4];
        float mx = -1e30f;
#pragma unroll
        for (int nt = 0; nt < 4; ++nt) {
            int col = nt * 16 + lm;
            x[nt] = (col < SEGL) ? sc[nt][r] * 0.125f : -1e9f;
            mx = fmaxf(mx, x[nt]);
        }
        for (int off = 8; off; off >>= 1) mx = fmaxf(mx, __shfl_xor(mx, off));
        float e[4], se = 0.f;
#pragma unroll
        for (int nt = 0; nt < 4; ++nt) { e[nt] = __expf(x[nt] - mx); se += e[nt]; }
        for (int off = 8; off; off >>= 1) se += __shfl_xor(se, off);
        float inv = 1.f / se;
        int row = wave * 16 + lq * 4 + r;
#pragma unroll
        for (int nt = 0; nt < 4; ++nt)
            qs[row][nt * 16 + lm] = f2b(e[nt] * inv);
    }
    __syncthreads();

    // PV
    ffrag oc[4];
#pragma unroll
    for (int dt = 0; dt < 4; ++dt) oc[dt] = (ffrag){0.f, 0.f, 0.f, 0.f};
#pragma unroll
    for (int kt = 0; kt < 2; ++kt) {
        bfrag a = *(const bfrag*)&qs[wave * 16 + lm][kt * 32 + lq * 8];
#pragma unroll
        for (int dt = 0; dt < 4; ++dt) {
            bfrag b = *(const bfrag*)&vt[dt * 16 + lm][kt * 32 + lq * 8];
            oc[dt] = __builtin_amdgcn_mfma_f32_16x16x32_bf16(a, b, oc[dt], 0, 0, 0);
        }
    }
#pragma unroll
    for (int r = 0; r < 4; ++r) {
        int i = wave * 16 + lq * 4 + r;
        if (i < SEGL) {
            ushort_t* op = O + (long long)(n * SEGL + i) * DMODEL + h * DHEAD + lm;
#pragma unroll
            for (int dt = 0; dt < 4; ++dt)
                op[dt * 16] = f2b(oc[dt][r]);
        }
    }
}

// add+LN unit (== add_ln_k body, 4 rows/unit). No LDS, no barriers.
template<bool OUTF32>
__device__ void dev_add_ln(int u,
    const ushort_t* __restrict__ A, int agrp, long long astride,
    const ushort_t* __restrict__ Bv,
    const float* __restrict__ gamma, const float* __restrict__ beta,
    void* __restrict__ O, int ogrp, long long ostride, int M)
{
    const int wave = threadIdx.x >> 6, lane = threadIdx.x & 63;
    const int r = u * 4 + wave;
    if (r >= M) return;
    const ushort_t* a = A + (long long)(r / agrp) * astride + (long long)(r % agrp) * DMODEL;
    const ushort_t* b = Bv + (long long)r * DMODEL;
    float x[8];
    {
        uint4 a4 = *(const uint4*)(a + lane * 8);
        uint4 b4 = *(const uint4*)(b + lane * 8);
        const unsigned* aa = (const unsigned*)&a4;
        const unsigned* bb = (const unsigned*)&b4;
#pragma unroll
        for (int c = 0; c < 4; ++c) {
            union { unsigned u; float f; } alo, ahi, blo, bhi;
            alo.u = aa[c] << 16; ahi.u = aa[c] & 0xffff0000u;
            blo.u = bb[c] << 16; bhi.u = bb[c] & 0xffff0000u;
            x[2 * c]     = alo.f + blo.f;
            x[2 * c + 1] = ahi.f + bhi.f;
        }
    }
    float s = 0.f, s2 = 0.f;
#pragma unroll
    for (int i = 0; i < 8; ++i) { s += x[i]; s2 = fmaf(x[i], x[i], s2); }
    for (int off = 32; off; off >>= 1) {
        s += __shfl_xor(s, off);
        s2 += __shfl_xor(s2, off);
    }
    const float mean = s * (1.f / DMODEL);
    const float var = s2 * (1.f / DMODEL) - mean * mean;
    const float inv = rsqrtf(var + 1e-5f);
    float4 g0 = *(const float4*)(gamma + lane * 8);
    float4 g1 = *(const float4*)(gamma + lane * 8 + 4);
    float4 be0 = *(const float4*)(beta + lane * 8);
    float4 be1 = *(const float4*)(beta + lane * 8 + 4);
    float y[8];
    y[0] = (x[0] - mean) * inv * g0.x + be0.x;
    y[1] = (x[1] - mean) * inv * g0.y + be0.y;
    y[2] = (x[2] - mean) * inv * g0.z + be0.z;
    y[3] = (x[3] - mean) * inv * g0.w + be0.w;
    y[4] = (x[4] - mean) * inv * g1.x + be1.x;
    y[5] = (x[5] - mean) * inv * g1.y + be1.y;
    y[6] = (x[6] - mean) * inv * g1.z + be1.z;
    y[7] = (x[7] - mean) * inv * g1.w + be1.w;
    if (OUTF32) {
        float* o = (float*)O + (long long)(r / ogrp) * ostride + (long long)(r % ogrp) * DMODEL;
        *(float4*)(o + lane * 8) = *(float4*)&y[0];
        *(float4*)(o + lane * 8 + 4) = *(float4*)&y[4];
    } else {
        ushort_t* o = (ushort_t*)O + (long long)(r / ogrp) * ostride + (long long)(r % ogrp) * DMODEL;
        ushort_t ob[8];
#pragma unroll
        for (int i = 0; i < 8; ++i) ob[i] = f2b(y[i]);
        *(uint4*)(o + lane * 8) = *(const uint4*)ob;
    }
}

// Persistent phase-2: all 15 connection steps; 6 phases/step, grid barriers
// between. Launched as a PLAIN kernel; grid size chosen host-side so all
// blocks are co-resident (validated via the occupancy API).
__global__ __launch_bounds__(256, 2) void phase2_k(
    const ushort_t* __restrict__ ENC, const ushort_t* __restrict__ QALL,
    const ushort_t* __restrict__ cKV, const ushort_t* __restrict__ cWoT,
    const ushort_t* __restrict__ cF1T, const ushort_t* __restrict__ cF2T,
    const float* __restrict__ cG1, const float* __restrict__ cB1,
    const float* __restrict__ cG2, const float* __restrict__ cB2,
    ushort_t* __restrict__ BUF4, ushort_t* __restrict__ BUF0,
    ushort_t* __restrict__ BUF2, ushort_t* __restrict__ MID,
    ushort_t* __restrict__ OUTB, float* __restrict__ out,
    unsigned* __restrict__ bar)
{
    __shared__ ushort_t smem[21504];   // 43008 B: max(cross_attn, gemm64)
    const int nblk = gridDim.x;
    const int gsz = nblk >> 3;                      // blocks per barrier group
    const int Ms = NB * SEGL;                       // 3200
    const long long SEQROW = (long long)NT * SEGL * DMODEL;  // 409600
    int p = 0;

    for (int t = 1; t < NT; ++t) {
        const ushort_t* prevA; int pg; long long ps;
        if (t == 1) { prevA = ENC;  pg = SEGL; ps = SEQROW; }
        else        { prevA = OUTB; pg = Ms;   ps = 0; }
        const ushort_t* currA = ENC + (long long)t * SEGL * DMODEL;

        // A: fused KV-projection + cross-attention -> BUF4 (512 units)
        for (int u = blockIdx.x; u < NB * NHEAD; u += nblk)
            dev_cross_attn(smem, u,
                           QALL + (long long)(t - 1) * 25600, 750LL * 512, 512,
                           prevA, pg, ps, cKV, BUF4);
        gbar(bar, ++p, gsz);

        // B: Wo GEMM: 3200x512x512 -> BUF0 (400 units)
        for (int u = blockIdx.x; u < (512 / 64) * (Ms / 64); u += nblk)
            dev_gemm64(smem, u, BUF4, Ms, 0, cWoT, BUF0, Ms, 512, 512, 0);
        gbar(bar, ++p, gsz);

        // C: LN(curr + BUF0) -> BUF2 (800 units)
        for (int u = blockIdx.x; u < Ms / 4; u += nblk)
            dev_add_ln<false>(u, currA, SEGL, SEQROW, BUF0, cG1, cB1,
                              BUF2, Ms, 0, Ms);
        gbar(bar, ++p, gsz);

        // D: F1 GEMM + relu: 3200x2048x512 -> MID (1600 units)
        for (int u = blockIdx.x; u < (2048 / 64) * (Ms / 64); u += nblk)
            dev_gemm64(smem, u, BUF2, Ms, 0, cF1T, MID, Ms, 2048, 512, 1);
        gbar(bar, ++p, gsz);

        // E: F2 GEMM: 3200x512x2048 -> BUF0 (400 units)
        for (int u = blockIdx.x; u < (512 / 64) * (Ms / 64); u += nblk)
            dev_gemm64(smem, u, MID, Ms, 0, cF2T, BUF0, Ms, 512, 2048, 0);
        gbar(bar, ++p, gsz);

        // F: LN(BUF2 + BUF0) -> OUTB (or f32 out on last step)
        if (t == NT - 1) {
            for (int u = blockIdx.x; u < Ms / 4; u += nblk)
                dev_add_ln<true>(u, BUF2, Ms, 0, BUF0, cG2, cB2,
                                 out, Ms, 0, Ms);
        } else {
            for (int u = blockIdx.x; u < Ms / 4; u += nblk)
                dev_add_ln<false>(u, BUF2, Ms, 0, BUF0, cG2, cB2,
                                  OUTB, Ms, 0, Ms);
        }
        gbar(bar, ++p, gsz);
    }
}

// ---------------------------------------------------------------------------
extern "C" void kernel_launch(void* const* d_in, const int* in_sizes, int n_in,
                              void* d_out, int out_size, void* d_ws, size_t ws_size,
                              hipStream_t stream)
{
    const float* seqs = (const float*)d_in[0];
    const int*   ends = (const int*)d_in[1];
    const float* eG1 = (const float*)d_in[7],  *eB1 = (const float*)d_in[8];
    const float* eG2 = (const float*)d_in[11], *eB2 = (const float*)d_in[12];
    const float* cG1 = (const float*)d_in[17], *cB1 = (const float*)d_in[18];
    const float* cG2 = (const float*)d_in[21], *cB2 = (const float*)d_in[22];
    float* out = (float*)d_out;

    const int G = (ws_size >= (size_t)470000000) ? 8 : 4;
    const long long CH = 1638400LL * G;

    ushort_t* ws = (ushort_t*)d_ws;
    const long long SEQROW = (long long)NT * SEGL * DMODEL;    // 409600
    ushort_t* SEQB = ws;
    ushort_t* WT   = SEQB + 26214400LL;
    ushort_t* ENC  = WT   + 6553600LL;
    ushort_t* BUF0 = ENC  + 26214400LL;
    ushort_t* QKV  = BUF0 + CH;
    ushort_t* BUF4 = QKV  + 3 * CH;
    ushort_t* BUF1 = BUF4 + CH;
    ushort_t* BUF2 = BUF1 + CH;
    ushort_t* MID  = BUF2 + CH;
    ushort_t* OUTB = MID  + 4 * CH;
    ushort_t* QALL = OUTB + 1638400LL;
    int*      lens = (int*)(QALL + 24576000LL);
    unsigned* bar  = (unsigned*)(lens + 1024);

    const ushort_t* eWinT = WT + 0;
    const ushort_t* WQKVe = WT + 262144;      // 1536 x 512
    const ushort_t* eWoT  = WT + 1048576;
    const ushort_t* eF1T  = WT + 1310720;     // 2048 x 512
    const ushort_t* eF2T  = WT + 2359296;     // 512 x 2048
    const ushort_t* cWqT  = WT + 3407872;
    const ushort_t* cKV   = WT + 3670016;     // 1024 x 512
    const ushort_t* cWoT  = WT + 4194304;
    const ushort_t* cF1T  = WT + 4456448;
    const ushort_t* cF2T  = WT + 5505024;

    struct WMap { int src; long long dst; int K, N; };
    const WMap wm[13] = {
        {2,  0,       512, 512},
        {3,  262144,  512, 512},
        {4,  524288,  512, 512},
        {5,  786432,  512, 512},
        {6,  1048576, 512, 512},
        {9,  1310720, 512, 2048},
        {10, 2359296, 2048, 512},
        {13, 3407872, 512, 512},
        {14, 3670016, 512, 512},
        {15, 3932160, 512, 512},
        {16, 4194304, 512, 512},
        {19, 4456448, 512, 2048},
        {20, 5505024, 2048, 512},
    };

    cvt_k<<<12800, 256, 0, stream>>>(seqs, SEQB, 26214400LL);
    for (int w = 0; w < 13; ++w) {
        dim3 g(wm[w].N / 32, wm[w].K / 32);
        wtrans_k<<<g, 256, 0, stream>>>((const float*)d_in[wm[w].src],
                                        WT + wm[w].dst, wm[w].K, wm[w].N);
    }
    lens_k<<<4, 256, 0, stream>>>(ends, lens, bar);

    auto gemmL = [&](const ushort_t* A, int agrp, long long astr, const ushort_t* Bt,
                     ushort_t* C, int M, int N, int K, int relu) {
        dim3 g(N / 128, M / 128);
        mfma_gemm<128, 128, 2, 2><<<g, 256, 0, stream>>>(A, agrp, astr, Bt, C, M, N, K, relu);
    };

    // ---------------- Phase 1: all encoders, chunks of G segments ----------
    const int Mc = NB * G * SEGL;
    for (int c = 0; c < NT / G; ++c) {
        const int t0 = c * G;
        const ushort_t* Abase = SEQB + (long long)t0 * SEGL * DMODEL;
        ushort_t* ENCc = ENC + (long long)t0 * SEGL * DMODEL;
        gemmL(Abase, G * SEGL, SEQROW, eWinT, BUF0, Mc, 512, 512, 0);
        gemmL(BUF0, Mc, 0, WQKVe, QKV, Mc, 1536, 512, 0);
        attn_mfma_k<<<NB * G * NHEAD, 256, 0, stream>>>(
            QKV, 50LL * 1536, 1536, QKV + 512, QKV + 1024, 50LL * 1536, 1536,
            BUF4, lens, G, t0);
        gemmL(BUF4, Mc, 0, eWoT, BUF1, Mc, 512, 512, 0);
        add_ln_k<false><<<Mc / 4, 256, 0, stream>>>(BUF0, Mc, 0, BUF1, eG1, eB1,
                                                    BUF2, Mc, 0, Mc);
        gemmL(BUF2, Mc, 0, eF1T, MID, Mc, 2048, 512, 1);
        gemmL(MID, Mc, 0, eF2T, BUF1, Mc, 512, 2048, 0);
        add_ln_k<false><<<Mc / 4, 256, 0, stream>>>(BUF2, Mc, 0, BUF1, eG2, eB2,
                                                    ENCc, G * SEGL, SEQROW, Mc);
    }

    // Batched Q projections for ALL phase-2 steps
    gemmL(ENC + 25600, 750, SEQROW, cWqT, QALL, 48000, 512, 512, 0);

    // ---------------- Phase 2: single persistent kernel (plain launch) -----
    {
        // Co-residency check: grid must not exceed occupancy * numCU (256).
        static int grid = 0;
        if (grid == 0) {
            int occ = 0;
            if (hipOccupancyMaxActiveBlocksPerMultiprocessor(
                    &occ, phase2_k, 256, 0) != hipSuccess || occ < 1)
                occ = 1;
            grid = (occ >= 2) ? 512 : 256;
        }
        phase2_k<<<grid, 256, 0, stream>>>(
            ENC, QALL, cKV, cWoT, cF1T, cF2T,
            cG1, cB1, cG2, cB2,
            BUF4, BUF0, BUF2, MID, OUTB, out, bar);
    }
}